// Round 1
// baseline (39.452 us; speedup 1.0000x reference)
//
#include <hip/hip_runtime.h>

// SNNMaxPool2d winner-take-all forward.
// x: [B, C, H, W, T] f32 spikes (0/1). out: [B, C, OH, OW, T] f32 one-hot of
// earliest spiking timestep per 2x2 (stride 2) window, zeros if no spike.
//
// One wave64 per output pixel. T=100: lane l covers t = l and t = l+64.
// Window rows (h,w)+(h,w+1) are contiguous (200 floats); (h+1,*) likewise.

#define T_DIM 100

__global__ __launch_bounds__(256) void snn_maxpool_wta_kernel(
    const float* __restrict__ x, float* __restrict__ out,
    int C, int H, int W, int OH, int OW, int n_pix)
{
    const int T = T_DIM;
    const int wave = threadIdx.x >> 6;      // 0..3
    const int lane = threadIdx.x & 63;
    const int p = blockIdx.x * 4 + wave;    // output pixel index
    if (p >= n_pix) return;

    int ow = p % OW;
    int tmp = p / OW;
    int oh = tmp % OH;
    tmp /= OH;
    int c = tmp % C;
    int b = tmp / C;

    const int h = oh * 2, w = ow * 2;
    const size_t row0_off = ((((size_t)b * C + c) * H + h) * W + w) * T;
    const float* __restrict__ r0 = x + row0_off;            // (h, w)   : t 0..99, then (h, w+1)
    const float* __restrict__ r1 = r0 + (size_t)W * T;      // (h+1, w) : t 0..99, then (h+1, w+1)

    // per-lane earliest spiking t (sentinel = T)
    int mint = T;
    #pragma unroll
    for (int t = lane; t < T; t += 64) {
        float v = fmaxf(fmaxf(r0[t], r0[T + t]), fmaxf(r1[t], r1[T + t]));
        if (v > 0.0f && t < mint) mint = t;
    }

    // wave64 min-reduce
    #pragma unroll
    for (int off = 32; off >= 1; off >>= 1) {
        int o = __shfl_xor(mint, off, 64);
        mint = min(mint, o);
    }

    // write one-hot (every element written -> poison-safe)
    float* __restrict__ o = out + (size_t)p * T;
    #pragma unroll
    for (int t = lane; t < T; t += 64)
        o[t] = (t == mint) ? 1.0f : 0.0f;
}

extern "C" void kernel_launch(void* const* d_in, const int* in_sizes, int n_in,
                              void* d_out, int out_size, void* d_ws, size_t ws_size,
                              hipStream_t stream) {
    const float* x = (const float*)d_in[0];
    float* out = (float*)d_out;

    const int B = 4, C = 32, H = 64, W = 64;
    const int OH = (H - 2) / 2 + 1;   // 32
    const int OW = (W - 2) / 2 + 1;   // 32
    const int n_pix = B * C * OH * OW;  // 131072

    const int waves_per_block = 4;      // 256 threads
    const int blocks = (n_pix + waves_per_block - 1) / waves_per_block;

    snn_maxpool_wta_kernel<<<blocks, 256, 0, stream>>>(x, out, C, H, W, OH, OW, n_pix);
}

// Round 2
// 34.018 us; speedup vs baseline: 1.1597x; 1.1597x over previous
//
#include <hip/hip_runtime.h>

// SNNMaxPool2d winner-take-all forward, sparsity-exploiting early exit.
// x: [B, C, H, W, T] f32 spikes (0/1). out: [B, C, OH, OW, T] f32 one-hot of
// earliest spiking timestep per 2x2 (stride 2) window, zeros if no spike.
//
// One wave64 per output pixel. Lane = cell*16 + t_local: the wave checks all
// 4 window cells over 16 consecutive timesteps per iteration. P(no spike in
// 16 steps | p=0.1, 4 cells) = 0.9^64 ~ 0.0012, so ~99.9% of windows resolve
// after one 256B chunk instead of reading all 1600B. Windows are
// non-overlapping, so skipped bytes are never fetched at all.

#define T_DIM 100

__global__ __launch_bounds__(256) void snn_maxpool_wta_kernel(
    const float* __restrict__ x, float* __restrict__ out,
    int C, int H, int W, int OH, int OW, int n_pix)
{
    const int T = T_DIM;
    const int wave = threadIdx.x >> 6;      // 0..3
    const int lane = threadIdx.x & 63;
    const int p = blockIdx.x * 4 + wave;    // output pixel index
    if (p >= n_pix) return;

    int ow = p % OW;
    int tmp = p / OW;
    int oh = tmp % OH;
    tmp /= OH;
    int c = tmp % C;
    int b = tmp / C;

    const int h = oh * 2, w = ow * 2;
    const size_t row0_off = ((((size_t)b * C + c) * H + h) * W + w) * T;
    const float* __restrict__ r0 = x + row0_off;        // (h, w): t 0..99, then (h, w+1)
    const float* __restrict__ r1 = r0 + (size_t)W * T;  // (h+1, w), then (h+1, w+1)

    const int cell = lane >> 4;   // 0..3 -> which window cell
    const int tl   = lane & 15;   // t offset within chunk

    // per-cell time series base pointer
    const float* __restrict__ myrow =
        ((cell & 2) ? r1 : r0) + ((cell & 1) ? T : 0);

    int mint = T;   // sentinel: no spike
    #pragma unroll 1
    for (int tb = 0; tb < T; tb += 16) {
        int t = tb + tl;
        float v = (t < T) ? myrow[t] : 0.0f;
        unsigned long long m = __ballot(v > 0.0f);
        if (m) {
            // fold the 4 cell groups; lowest set bit of low 16 = min t_local
            unsigned long long fold = m | (m >> 16) | (m >> 32) | (m >> 48);
            mint = tb + (int)__builtin_ctzll(fold & 0xFFFFull);
            break;
        }
    }

    // write one-hot: 25 float4 stores cover 100 floats, contiguous 400B
    float* __restrict__ o = out + (size_t)p * T;
    if (lane < 25) {
        const int t0 = lane * 4;
        float4 v;
        v.x = (t0     == mint) ? 1.0f : 0.0f;
        v.y = (t0 + 1 == mint) ? 1.0f : 0.0f;
        v.z = (t0 + 2 == mint) ? 1.0f : 0.0f;
        v.w = (t0 + 3 == mint) ? 1.0f : 0.0f;
        *reinterpret_cast<float4*>(o + t0) = v;
    }
}

extern "C" void kernel_launch(void* const* d_in, const int* in_sizes, int n_in,
                              void* d_out, int out_size, void* d_ws, size_t ws_size,
                              hipStream_t stream) {
    const float* x = (const float*)d_in[0];
    float* out = (float*)d_out;

    const int B = 4, C = 32, H = 64, W = 64;
    const int OH = (H - 2) / 2 + 1;   // 32
    const int OW = (W - 2) / 2 + 1;   // 32
    const int n_pix = B * C * OH * OW;  // 131072

    const int waves_per_block = 4;      // 256 threads
    const int blocks = (n_pix + waves_per_block - 1) / waves_per_block;

    snn_maxpool_wta_kernel<<<blocks, 256, 0, stream>>>(x, out, C, H, W, OH, OW, n_pix);
}

// Round 3
// 26.956 us; speedup vs baseline: 1.4636x; 1.2620x over previous
//
#include <hip/hip_runtime.h>

// SNNMaxPool2d winner-take-all forward, line-aligned sparse probe.
// x: [B=4, C=32, H=64, W=64, T=100] f32 spikes. out: [4,32,32,32,100] one-hot
// of earliest spiking t per 2x2/stride-2 window.
//
// One wave64 handles TWO windows (half-wave each). Per window: 4 cells x 8
// lanes x float4 = each cell's probe is exactly the 128B-aligned line
// containing its t=0 (junk floats before t=0 masked). 512B/window fetched,
// 100% line utilization. Probe min-t is valid iff < min coverage over cells;
// else (~5% of windows) dense-scan fallback.

#define T_DIM 100

__global__ __launch_bounds__(256) void snn_wta_kernel(
    const float* __restrict__ x, float* __restrict__ out, int n_pix)
{
    const int T = T_DIM;
    const int C = 32, H = 64, W = 64, OH = 32, OW = 32;

    const int wave = threadIdx.x >> 6;   // 0..3
    const int lane = threadIdx.x & 63;
    const int half = lane >> 5;          // which window of the pair
    const int q2   = lane & 31;          // lane within half
    const int cell = q2 >> 3;            // 0..3 window cell
    const int q    = q2 & 7;             // lane within cell (8 x float4 = 128B)

    const int p = (blockIdx.x * 4 + wave) * 2 + half;  // grid sized exactly
    if (p >= n_pix) return;

    const int ow = p & (OW - 1);
    int tmp = p >> 5;
    const int oh = tmp & (OH - 1);
    tmp >>= 5;
    const int c = tmp & (C - 1);
    const int b = tmp >> 5;

    const size_t base0 = ((((size_t)b * C + c) * H + oh * 2) * W + ow * 2) * T;
    const float* __restrict__ r0 = x + base0;          // (h,w) then (h,w+1)
    const float* __restrict__ A  = r0
        + ((cell & 2) ? (size_t)W * T : 0)
        + ((cell & 1) ? T : 0);

    // line-aligned probe: whole 128B line containing A
    const float* __restrict__ Ad =
        (const float*)((uintptr_t)A & ~(uintptr_t)127);
    const int moff = (int)(((uintptr_t)A & 127) >> 2);   // junk floats before t=0
    const float4 v = *(const float4*)(Ad + q * 4);
    const int t0 = q * 4 - moff;

    int lmint = T;
    {
        float vv0 = v.x, vv1 = v.y, vv2 = v.z, vv3 = v.w;
        if (t0 + 0 >= 0 && vv0 > 0.0f) lmint = min(lmint, t0 + 0);
        if (t0 + 1 >= 0 && vv1 > 0.0f) lmint = min(lmint, t0 + 1);
        if (t0 + 2 >= 0 && vv2 > 0.0f) lmint = min(lmint, t0 + 2);
        if (t0 + 3 >= 0 && vv3 > 0.0f) lmint = min(lmint, t0 + 3);
    }

    // half-wave (32-lane) min-reduce: offsets <32 stay within the half
    #pragma unroll
    for (int off = 16; off >= 1; off >>= 1)
        lmint = min(lmint, __shfl_xor(lmint, off, 64));

    // coverage: cells 0,2 share alignment; cells 1,3 share (r1-r0 = 25600 = 200 lines)
    const int m0 = (int)(((uintptr_t)r0 & 127) >> 2);
    const int m1 = (int)(((uintptr_t)(r0 + T) & 127) >> 2);
    const int cover_min = 32 - max(m0, m1);

    if (lmint >= cover_min) {
        // rare fallback: dense strided scan (8 lanes per cell, stride 8)
        int fb = T;
        for (int t = q; t < T; t += 8) {
            if (A[t] > 0.0f) { fb = t; break; }
        }
        lmint = fb;
        #pragma unroll
        for (int off = 16; off >= 1; off >>= 1)
            lmint = min(lmint, __shfl_xor(lmint, off, 64));
    }

    // write one-hot: 25 float4 per window, contiguous 400B
    float* __restrict__ o = out + (size_t)p * T;
    if (q2 < 25) {
        const int t0w = q2 * 4;
        float4 w4;
        w4.x = (t0w     == lmint) ? 1.0f : 0.0f;
        w4.y = (t0w + 1 == lmint) ? 1.0f : 0.0f;
        w4.z = (t0w + 2 == lmint) ? 1.0f : 0.0f;
        w4.w = (t0w + 3 == lmint) ? 1.0f : 0.0f;
        *reinterpret_cast<float4*>(o + t0w) = w4;
    }
}

extern "C" void kernel_launch(void* const* d_in, const int* in_sizes, int n_in,
                              void* d_out, int out_size, void* d_ws, size_t ws_size,
                              hipStream_t stream) {
    const float* x = (const float*)d_in[0];
    float* out = (float*)d_out;

    const int B = 4, C = 32, OH = 32, OW = 32;
    const int n_pix = B * C * OH * OW;          // 131072
    const int blocks = n_pix / 8;               // 2 windows/wave, 4 waves/block

    snn_wta_kernel<<<blocks, 256, 0, stream>>>(x, out, n_pix);
}